// Round 12
// baseline (263.075 us; speedup 1.0000x reference)
//
#include <hip/hip_runtime.h>
#include <hip/hip_fp16.h>

// GCN 2-layer, padded-CSR (CAP=64 u16 slots/node), fp16 gather operand.
// Round-12 structure (4 enqueues):
//   memset cnt
//   k_fused     : blocks [0,1024) gemm1: P1 = x @ W1 (UNSCALED fp16)
//                 blocks [1024,9216) fill: cnt[dst]++, csr[dst*64+pos]=src
//   k_agg1_gemm2: per node v: acc = dv*P1[v] + sum dinv[s]*P1[s]  (dinv via
//                 on-the-fly rsqrt(cnt+1)); H = relu(dv*acc + b1) held in
//                 registers (all 64 lanes have full H after butterfly);
//                 P2[v][lane] = fp16(dv * sum_k H[k]*W2[k][lane])
//                 (shfl-broadcast H + L1-hot W2 row loads; H never hits HBM)
//   k_agg2      : out[v] = dv * (P2[v] + sum P2[s]) + b2   (fp32)
// Aggregates run 16 edges in flight (4 subgroups x 4-deep unroll).

#define N_NODES 65536
#define E_EDGES 1048576
#define F_IN    128
#define F_HID   64
#define CAPSH   6                                 // 64 slots per node
#define GEMM1_BLOCKS (N_NODES / 64)               // 1024
#define FILL_BLOCKS  ((E_EDGES / 4 / 256) * 8)    // 8192

__device__ inline unsigned int pack_h2(float a, float b) {
    __half2 h = __floats2half2_rn(a, b);
    return *(unsigned int*)&h;
}

__device__ inline float4 h4_to_f4(uint2 q) {
    __half2 a = *(__half2*)&q.x;
    __half2 b = *(__half2*)&q.y;
    float2 fa = __half22float2(a), fb = __half22float2(b);
    return make_float4(fa.x, fa.y, fb.x, fb.y);
}

// Block = 64 nodes x 4 waves. Wave w: cols [16w,16w+16). W wave-uniform ->
// scalar loads; h per-lane float4. P[v](fp16) = h[v] @ W (unscaled).
template <int F_K>
__device__ inline void gemm_body(const float* __restrict__ h, const float* __restrict__ W,
                                 __half* __restrict__ P, int bid) {
    int wave = __builtin_amdgcn_readfirstlane(threadIdx.x >> 6);  // 0..3, SGPR
    int lane = threadIdx.x & 63;
    int v = bid * 64 + lane;
    const float4* hr = (const float4*)(h + (size_t)v * F_K);
    float4 acc[4];
#pragma unroll
    for (int j = 0; j < 4; ++j) acc[j] = make_float4(0.f, 0.f, 0.f, 0.f);
#pragma unroll 4
    for (int kb = 0; kb < F_K / 4; ++kb) {
        float4 hv = hr[kb];
#pragma unroll
        for (int r = 0; r < 4; ++r) {
            float hk = r == 0 ? hv.x : r == 1 ? hv.y : r == 2 ? hv.z : hv.w;
            const float4* Wr = (const float4*)(W + (size_t)(kb * 4 + r) * 64 + (wave << 4));
#pragma unroll
            for (int j = 0; j < 4; ++j) {
                float4 w = Wr[j];          // uniform across wave -> s_load
                acc[j].x = fmaf(hk, w.x, acc[j].x);
                acc[j].y = fmaf(hk, w.y, acc[j].y);
                acc[j].z = fmaf(hk, w.z, acc[j].z);
                acc[j].w = fmaf(hk, w.w, acc[j].w);
            }
        }
    }
    __half* Pr = P + (size_t)v * 64 + (wave << 4);
    uint4 q0, q1;
    q0.x = pack_h2(acc[0].x, acc[0].y); q0.y = pack_h2(acc[0].z, acc[0].w);
    q0.z = pack_h2(acc[1].x, acc[1].y); q0.w = pack_h2(acc[1].z, acc[1].w);
    q1.x = pack_h2(acc[2].x, acc[2].y); q1.y = pack_h2(acc[2].z, acc[2].w);
    q1.z = pack_h2(acc[3].x, acc[3].y); q1.w = pack_h2(acc[3].z, acc[3].w);
    ((uint4*)Pr)[0] = q0;
    ((uint4*)Pr)[1] = q1;
}

// gemm1 + CSR fill co-resident (independent work; P1 unscaled so gemm never
// reads cnt which fill concurrently updates).
__global__ __launch_bounds__(256) void k_fused(
        const float* __restrict__ x, const float* __restrict__ W1,
        __half* __restrict__ P,
        const int* __restrict__ src, const int* __restrict__ dst,
        int* __restrict__ cnt, unsigned short* __restrict__ csr) {
    if (blockIdx.x < GEMM1_BLOCKS) {
        gemm_body<F_IN>(x, W1, P, blockIdx.x);
    } else {
        int fb    = blockIdx.x - GEMM1_BLOCKS;
        int g     = fb & 7;                        // XCD-partitioned dst range
        int chunk = fb >> 3;
        int i     = chunk * blockDim.x + threadIdx.x;
        int4 d = ((const int4*)dst)[i];
#pragma unroll
        for (int k = 0; k < 4; ++k) {
            int dv = k == 0 ? d.x : k == 1 ? d.y : k == 2 ? d.z : d.w;
            if ((dv >> 13) == g) {
                int pos = atomicAdd(&cnt[dv], 1);
                csr[(dv << CAPSH) + pos] = (unsigned short)src[4 * i + k];
            }
        }
    }
}

// One wave per node. Aggregate P1 with per-src on-the-fly rsqrt scaling,
// butterfly fold (every lane ends with full H-row segment for its col4),
// relu, then gemm2 via shfl-broadcast + L1-hot W2 rows. Writes P2 (fp16).
__global__ __launch_bounds__(256) void k_agg1_gemm2(
        const __half* __restrict__ P1, const unsigned short* __restrict__ csr,
        const int* __restrict__ cnt, const float* __restrict__ b1,
        const float* __restrict__ W2, __half* __restrict__ P2) {
    int lane = threadIdx.x & 63;
    int sub  = lane >> 4;              // subgroup 0..3
    int col4 = lane & 15;              // 4-half column group
    int wave  = (blockIdx.x * blockDim.x + threadIdx.x) >> 6;
    int nwave = (gridDim.x * blockDim.x) >> 6;
    float4 bias = ((const float4*)b1)[col4];
    for (int v = wave; v < N_NODES; v += nwave) {
        int c    = cnt[v];
        float dv = rsqrtf((float)c + 1.0f);
        int beg  = v << CAPSH;
        float4 acc = make_float4(0.f, 0.f, 0.f, 0.f);
        if (sub == 0) {                // self loop rides in subgroup 0
            float4 p = h4_to_f4(((const uint2*)(P1 + (size_t)v * 64))[col4]);
            acc.x = dv * p.x; acc.y = dv * p.y; acc.z = dv * p.z; acc.w = dv * p.w;
        }
        for (int i = 0; i < c; i += 16) {
#pragma unroll
            for (int u = 0; u < 4; ++u) {
                int e = i + sub + 4 * u;
                if (e < c) {
                    int s = csr[beg + e];
                    float f = rsqrtf((float)cnt[s] + 1.0f);
                    float4 p = h4_to_f4(((const uint2*)(P1 + (size_t)s * 64))[col4]);
                    acc.x = fmaf(f, p.x, acc.x); acc.y = fmaf(f, p.y, acc.y);
                    acc.z = fmaf(f, p.z, acc.z); acc.w = fmaf(f, p.w, acc.w);
                }
            }
        }
        // butterfly: after xor16+xor32 every lane holds the full column sum
        acc.x += __shfl_xor(acc.x, 16); acc.y += __shfl_xor(acc.y, 16);
        acc.z += __shfl_xor(acc.z, 16); acc.w += __shfl_xor(acc.w, 16);
        acc.x += __shfl_xor(acc.x, 32); acc.y += __shfl_xor(acc.y, 32);
        acc.z += __shfl_xor(acc.z, 32); acc.w += __shfl_xor(acc.w, 32);
        // H row (relu), valid on ALL lanes for cols [4*col4, 4*col4+4)
        float4 h;
        h.x = dv * acc.x + bias.x; h.x = h.x > 0.f ? h.x : 0.f;
        h.y = dv * acc.y + bias.y; h.y = h.y > 0.f ? h.y : 0.f;
        h.z = dv * acc.z + bias.z; h.z = h.z > 0.f ? h.z : 0.f;
        h.w = dv * acc.w + bias.w; h.w = h.w > 0.f ? h.w : 0.f;
        // gemm2: lane j computes P2[v][j]; H[k] broadcast from lane k>>2
        float p2 = 0.f;
#pragma unroll
        for (int k16 = 0; k16 < 16; ++k16) {
            float hx = __shfl(h.x, k16);   // uniform src lane -> readlane/SGPR
            float hy = __shfl(h.y, k16);
            float hz = __shfl(h.z, k16);
            float hw = __shfl(h.w, k16);
            const float* Wr = W2 + (size_t)(k16 * 4) * 64 + lane;
            p2 = fmaf(hx, Wr[0],   p2);    // W2[4k16+0][lane], L1-hot
            p2 = fmaf(hy, Wr[64],  p2);
            p2 = fmaf(hz, Wr[128], p2);
            p2 = fmaf(hw, Wr[192], p2);
        }
        P2[(size_t)v * 64 + lane] = __float2half_rn(p2 * dv);
    }
}

// One wave per node; 16 edges in flight. out = dv*(P2[v]+sum P2[s]) + b2.
__global__ __launch_bounds__(256) void k_agg2(
        const __half* __restrict__ P, const unsigned short* __restrict__ csr,
        const int* __restrict__ cnt, const float* __restrict__ b,
        float* __restrict__ out) {
    int lane = threadIdx.x & 63;
    int sub  = lane >> 4;
    int col4 = lane & 15;
    int wave  = (blockIdx.x * blockDim.x + threadIdx.x) >> 6;
    int nwave = (gridDim.x * blockDim.x) >> 6;
    float4 bias = ((const float4*)b)[col4];
    for (int v = wave; v < N_NODES; v += nwave) {
        int c    = cnt[v];
        float dv = rsqrtf((float)c + 1.0f);
        int beg  = v << CAPSH;
        float4 acc = make_float4(0.f, 0.f, 0.f, 0.f);
        if (sub == 0) {                // self loop
            float4 p = h4_to_f4(((const uint2*)(P + (size_t)v * 64))[col4]);
            acc = p;
        }
        for (int i = 0; i < c; i += 16) {
#pragma unroll
            for (int u = 0; u < 4; ++u) {
                int e = i + sub + 4 * u;
                if (e < c) {
                    int s = csr[beg + e];
                    float4 p = h4_to_f4(((const uint2*)(P + (size_t)s * 64))[col4]);
                    acc.x += p.x; acc.y += p.y; acc.z += p.z; acc.w += p.w;
                }
            }
        }
        acc.x += __shfl_xor(acc.x, 16); acc.y += __shfl_xor(acc.y, 16);
        acc.z += __shfl_xor(acc.z, 16); acc.w += __shfl_xor(acc.w, 16);
        acc.x += __shfl_xor(acc.x, 32); acc.y += __shfl_xor(acc.y, 32);
        acc.z += __shfl_xor(acc.z, 32); acc.w += __shfl_xor(acc.w, 32);
        if (lane < 16) {
            float4 o;
            o.x = dv * acc.x + bias.x;
            o.y = dv * acc.y + bias.y;
            o.z = dv * acc.z + bias.z;
            o.w = dv * acc.w + bias.w;
            ((float4*)(out + (size_t)v * 64))[col4] = o;
        }
    }
}

extern "C" void kernel_launch(void* const* d_in, const int* in_sizes, int n_in,
                              void* d_out, int out_size, void* d_ws, size_t ws_size,
                              hipStream_t stream) {
    const float* x   = (const float*)d_in[0];
    const int*   ei  = (const int*)d_in[1];      // [2, E]: src row, dst row
    const float* W1  = (const float*)d_in[2];
    const float* b1  = (const float*)d_in[3];
    const float* W2  = (const float*)d_in[4];
    const float* b2  = (const float*)d_in[5];
    float*       out = (float*)d_out;

    const int* src = ei;
    const int* dst = ei + E_EDGES;

    int*            cnt = (int*)d_ws;                        // N ints
    unsigned short* csr = (unsigned short*)(cnt + N_NODES);  // N*64 u16 (8MB)
    __half*         P1  = (__half*)(csr + ((size_t)N_NODES << CAPSH)); // N*64 fp16
    __half*         P2  = P1 + (size_t)N_NODES * 64;         // N*64 fp16

    hipMemsetAsync(cnt, 0, N_NODES * sizeof(int), stream);

    // gemm1 (unscaled) + CSR fill, co-resident in one dispatch
    k_fused<<<GEMM1_BLOCKS + FILL_BLOCKS, 256, 0, stream>>>(x, W1, P1, src, dst, cnt, csr);

    // agg1 (+relu +b1) fused with gemm2 -> P2 (H never touches HBM)
    k_agg1_gemm2<<<4096, 256, 0, stream>>>(P1, csr, cnt, b1, W2, P2);

    // agg2 -> out
    k_agg2<<<4096, 256, 0, stream>>>(P2, csr, cnt, b2, out);
}

// Round 13
// 208.415 us; speedup vs baseline: 1.2623x; 1.2623x over previous
//
#include <hip/hip_runtime.h>
#include <hip/hip_fp16.h>

// GCN 2-layer, padded-CSR (CAP=64 u16 slots/node), fp16 gather operand.
// Round-13 structure (6 enqueues):
//   memset cnt
//   k_fused : blocks [0,1024)  gemm1: P1 = x @ W1 (UNSCALED fp16)
//             blocks [1024,9216) fill: cnt[dst]++, csr[dst*64+pos]=src
//   k_scale : P1[v] *= rsqrt(cnt[v]+1)          (16 MB pass, ~5 us)
//   k_agg<relu> : H = relu(dv*(P1[v] + sum P1[s]) + b1)  -> d_out (fp32)
//   k_gemm  : P2 = rsqrt(cnt+1) * (H @ W2)      (fp16)
//   k_agg<>     : out = dv*(P2[v] + sum P2[s]) + b2
// Aggregate: ONE coalesced u16 load grabs all 64 csr slots of the node;
// per-edge src ids come from __shfl (register) -> the P-row gather is the
// only memory op per edge; 16 edges (4/lane) in flight.

#define N_NODES 65536
#define E_EDGES 1048576
#define F_IN    128
#define F_HID   64
#define CAPSH   6                                 // 64 slots per node
#define GEMM1_BLOCKS (N_NODES / 64)               // 1024
#define FILL_BLOCKS  ((E_EDGES / 4 / 256) * 8)    // 8192

__device__ inline unsigned int pack_h2(float a, float b) {
    __half2 h = __floats2half2_rn(a, b);
    return *(unsigned int*)&h;
}

__device__ inline float4 h4_to_f4(uint2 q) {
    __half2 a = *(__half2*)&q.x;
    __half2 b = *(__half2*)&q.y;
    float2 fa = __half22float2(a), fb = __half22float2(b);
    return make_float4(fa.x, fa.y, fb.x, fb.y);
}

// Block = 64 nodes x 4 waves. Wave w: cols [16w,16w+16). W wave-uniform ->
// scalar loads; h per-lane float4. P[v](fp16) = scale * (h[v] @ W).
// SCALED: scale = rsqrt(cnt[v]+1), else 1.
template <int F_K, bool SCALED>
__device__ inline void gemm_body(const float* __restrict__ h, const float* __restrict__ W,
                                 const int* __restrict__ cnt, __half* __restrict__ P,
                                 int bid) {
    int wave = __builtin_amdgcn_readfirstlane(threadIdx.x >> 6);  // 0..3, SGPR
    int lane = threadIdx.x & 63;
    int v = bid * 64 + lane;
    const float4* hr = (const float4*)(h + (size_t)v * F_K);
    float4 acc[4];
#pragma unroll
    for (int j = 0; j < 4; ++j) acc[j] = make_float4(0.f, 0.f, 0.f, 0.f);
#pragma unroll 4
    for (int kb = 0; kb < F_K / 4; ++kb) {
        float4 hv = hr[kb];
#pragma unroll
        for (int r = 0; r < 4; ++r) {
            float hk = r == 0 ? hv.x : r == 1 ? hv.y : r == 2 ? hv.z : hv.w;
            const float4* Wr = (const float4*)(W + (size_t)(kb * 4 + r) * 64 + (wave << 4));
#pragma unroll
            for (int j = 0; j < 4; ++j) {
                float4 w = Wr[j];          // uniform across wave -> s_load
                acc[j].x = fmaf(hk, w.x, acc[j].x);
                acc[j].y = fmaf(hk, w.y, acc[j].y);
                acc[j].z = fmaf(hk, w.z, acc[j].z);
                acc[j].w = fmaf(hk, w.w, acc[j].w);
            }
        }
    }
    float s = SCALED ? rsqrtf((float)cnt[v] + 1.0f) : 1.0f;
    __half* Pr = P + (size_t)v * 64 + (wave << 4);
    uint4 q0, q1;
    q0.x = pack_h2(acc[0].x * s, acc[0].y * s); q0.y = pack_h2(acc[0].z * s, acc[0].w * s);
    q0.z = pack_h2(acc[1].x * s, acc[1].y * s); q0.w = pack_h2(acc[1].z * s, acc[1].w * s);
    q1.x = pack_h2(acc[2].x * s, acc[2].y * s); q1.y = pack_h2(acc[2].z * s, acc[2].w * s);
    q1.z = pack_h2(acc[3].x * s, acc[3].y * s); q1.w = pack_h2(acc[3].z * s, acc[3].w * s);
    ((uint4*)Pr)[0] = q0;
    ((uint4*)Pr)[1] = q1;
}

// gemm1 + CSR fill co-resident (independent work; P1 unscaled so gemm never
// reads cnt which fill concurrently updates).
__global__ __launch_bounds__(256) void k_fused(
        const float* __restrict__ x, const float* __restrict__ W1,
        __half* __restrict__ P,
        const int* __restrict__ src, const int* __restrict__ dst,
        int* __restrict__ cnt, unsigned short* __restrict__ csr) {
    if (blockIdx.x < GEMM1_BLOCKS) {
        gemm_body<F_IN, false>(x, W1, nullptr, P, blockIdx.x);
    } else {
        int fb    = blockIdx.x - GEMM1_BLOCKS;
        int g     = fb & 7;                        // XCD-partitioned dst range
        int chunk = fb >> 3;
        int i     = chunk * blockDim.x + threadIdx.x;
        int4 d = ((const int4*)dst)[i];
#pragma unroll
        for (int k = 0; k < 4; ++k) {
            int dv = k == 0 ? d.x : k == 1 ? d.y : k == 2 ? d.z : d.w;
            if ((dv >> 13) == g) {
                int pos = atomicAdd(&cnt[dv], 1);
                csr[(dv << CAPSH) + pos] = (unsigned short)src[4 * i + k];
            }
        }
    }
}

// P1[v] *= rsqrt(cnt[v]+1). 4 threads per row, 32B (16 halves) each.
__global__ __launch_bounds__(256) void k_scale(
        __half* __restrict__ P, const int* __restrict__ cnt) {
    int t = blockIdx.x * blockDim.x + threadIdx.x;
    int v = t >> 2;
    float dv = rsqrtf((float)cnt[v] + 1.0f);
    uint4* p = (uint4*)(P + (size_t)v * 64) + (t & 3) * 2;
#pragma unroll
    for (int q = 0; q < 2; ++q) {
        uint4 u = p[q];
        unsigned int* w = (unsigned int*)&u;
#pragma unroll
        for (int j = 0; j < 4; ++j) {
            __half2 h = *(__half2*)&w[j];
            float2 f = __half22float2(h);
            w[j] = pack_h2(f.x * dv, f.y * dv);
        }
        p[q] = u;
    }
}

template <int F_K>
__global__ __launch_bounds__(256) void k_gemm(
        const float* __restrict__ h, const float* __restrict__ W,
        const int* __restrict__ cnt, __half* __restrict__ P) {
    gemm_body<F_K, true>(h, W, cnt, P, blockIdx.x);
}

// One wave per node. ONE coalesced u16 load = all 64 csr slots; src ids via
// __shfl. 16 gathers in flight (4 subgroups x 4-deep). P prescaled by dinv.
// out[v] = act(dv * (P[v] + sum P[s]) + b)
template <bool RELU>
__global__ __launch_bounds__(256) void k_agg(
        const __half* __restrict__ P, const unsigned short* __restrict__ csr,
        const int* __restrict__ cnt, const float* __restrict__ b,
        float* __restrict__ out) {
    int lane = threadIdx.x & 63;
    int sub  = lane >> 4;              // subgroup 0..3
    int col4 = lane & 15;              // 4-half column group
    int wave  = (blockIdx.x * blockDim.x + threadIdx.x) >> 6;
    int nwave = (gridDim.x * blockDim.x) >> 6;
    float4 bias = ((const float4*)b)[col4];
    for (int v = wave; v < N_NODES; v += nwave) {
        int c    = cnt[v];
        float dv = rsqrtf((float)c + 1.0f);
        int sidx = csr[(v << CAPSH) + lane];   // all 64 slots, one 128B load
        float4 acc = make_float4(0.f, 0.f, 0.f, 0.f);
        if (sub == 0) {                // self loop rides in subgroup 0
            float4 p = h4_to_f4(((const uint2*)(P + (size_t)v * 64))[col4]);
            acc = p;
        }
        for (int i = 0; i < c; i += 16) {
#pragma unroll
            for (int u = 0; u < 4; ++u) {
                int e = i + sub + 4 * u;
                int s = __shfl(sidx, e);       // register-resident src id
                if (e < c) {
                    float4 p = h4_to_f4(((const uint2*)(P + (size_t)s * 64))[col4]);
                    acc.x += p.x; acc.y += p.y; acc.z += p.z; acc.w += p.w;
                }
            }
        }
        // fold the 4 subgroup partials: xor 16 then xor 32
        acc.x += __shfl_xor(acc.x, 16); acc.y += __shfl_xor(acc.y, 16);
        acc.z += __shfl_xor(acc.z, 16); acc.w += __shfl_xor(acc.w, 16);
        acc.x += __shfl_xor(acc.x, 32); acc.y += __shfl_xor(acc.y, 32);
        acc.z += __shfl_xor(acc.z, 32); acc.w += __shfl_xor(acc.w, 32);
        if (lane < 16) {
            float4 o;
            o.x = dv * acc.x + bias.x;
            o.y = dv * acc.y + bias.y;
            o.z = dv * acc.z + bias.z;
            o.w = dv * acc.w + bias.w;
            if (RELU) {
                o.x = o.x > 0.f ? o.x : 0.f;
                o.y = o.y > 0.f ? o.y : 0.f;
                o.z = o.z > 0.f ? o.z : 0.f;
                o.w = o.w > 0.f ? o.w : 0.f;
            }
            ((float4*)(out + (size_t)v * 64))[col4] = o;
        }
    }
}

extern "C" void kernel_launch(void* const* d_in, const int* in_sizes, int n_in,
                              void* d_out, int out_size, void* d_ws, size_t ws_size,
                              hipStream_t stream) {
    const float* x   = (const float*)d_in[0];
    const int*   ei  = (const int*)d_in[1];      // [2, E]: src row, dst row
    const float* W1  = (const float*)d_in[2];
    const float* b1  = (const float*)d_in[3];
    const float* W2  = (const float*)d_in[4];
    const float* b2  = (const float*)d_in[5];
    float*       out = (float*)d_out;

    const int* src = ei;
    const int* dst = ei + E_EDGES;

    int*            cnt = (int*)d_ws;                        // N ints
    unsigned short* csr = (unsigned short*)(cnt + N_NODES);  // N*64 u16 (8MB)
    __half*         P1  = (__half*)(csr + ((size_t)N_NODES << CAPSH)); // N*64 fp16
    __half*         P2  = P1 + (size_t)N_NODES * 64;         // N*64 fp16
    float*          H   = out;                               // layer-1 output in d_out

    hipMemsetAsync(cnt, 0, N_NODES * sizeof(int), stream);

    // gemm1 (unscaled) + CSR fill, co-resident in one dispatch
    k_fused<<<GEMM1_BLOCKS + FILL_BLOCKS, 256, 0, stream>>>(x, W1, P1, src, dst, cnt, csr);

    // P1 *= dinv  (prescale so aggregates need no per-edge cnt lookups)
    k_scale<<<N_NODES * 4 / 256, 256, 0, stream>>>(P1, cnt);

    // Layer 1 aggregate -> H (relu)
    k_agg<true><<<4096, 256, 0, stream>>>(P1, csr, cnt, b1, H);

    // Layer 2: H -> P2 (prescaled), aggregate -> out
    k_gemm<F_HID><<<N_NODES / 64, 256, 0, stream>>>(H, W2, cnt, P2);
    k_agg<false><<<4096, 256, 0, stream>>>(P2, csr, cnt, b2, out);
}

// Round 14
// 199.834 us; speedup vs baseline: 1.3165x; 1.0429x over previous
//
#include <hip/hip_runtime.h>
#include <hip/hip_fp16.h>

// GCN 2-layer, padded-CSR (CAP=64 u16 slots/node), fp16 gather operand.
// Round-14 structure (6 enqueues):
//   memset cnt
//   k_fused : 9216 blocks in 72-windows: r=blockIdx%72; r<64 -> fill,
//             r>=64 -> gemm1 (P1 = x @ W1, unscaled fp16). Sprinkling keeps
//             gemm+fill co-resident (true overlap); r<64 preserves
//             fb&7 == blockIdx&7 XCD alignment for the csr partition.
//   k_scale : P1[v] *= rsqrt(cnt[v]+1)
//   k_agg<relu> : H = relu(dv*(P1[v] + sum P1[s]) + b1)  -> d_out (fp32)
//   k_gemm  : P2 = rsqrt(cnt+1) * (H @ W2)  (fp16)
//   k_agg<>     : out = dv*(P2[v] + sum P2[s]) + b2
// Aggregate: one coalesced u16 load = all 64 csr slots (src ids via shfl);
// next node's cnt/csr/self-row PREFETCHED before current node's gathers
// (breaks the csr->gather latency chain); gathers BRANCHLESS (always load,
// cndmask the value by e<c) so all 16 edge-gathers stay in flight.

#define N_NODES 65536
#define E_EDGES 1048576
#define F_IN    128
#define F_HID   64
#define CAPSH   6                                 // 64 slots per node
#define FUSED_BLOCKS 9216                         // 128 windows of 72

__device__ inline unsigned int pack_h2(float a, float b) {
    __half2 h = __floats2half2_rn(a, b);
    return *(unsigned int*)&h;
}

__device__ inline float4 h4_to_f4(uint2 q) {
    __half2 a = *(__half2*)&q.x;
    __half2 b = *(__half2*)&q.y;
    float2 fa = __half22float2(a), fb = __half22float2(b);
    return make_float4(fa.x, fa.y, fb.x, fb.y);
}

// Block = 64 nodes x 4 waves. Wave w: cols [16w,16w+16). W wave-uniform ->
// scalar loads; h per-lane float4. P[v](fp16) = scale * (h[v] @ W).
template <int F_K, bool SCALED>
__device__ inline void gemm_body(const float* __restrict__ h, const float* __restrict__ W,
                                 const int* __restrict__ cnt, __half* __restrict__ P,
                                 int bid) {
    int wave = __builtin_amdgcn_readfirstlane(threadIdx.x >> 6);  // 0..3, SGPR
    int lane = threadIdx.x & 63;
    int v = bid * 64 + lane;
    const float4* hr = (const float4*)(h + (size_t)v * F_K);
    float4 acc[4];
#pragma unroll
    for (int j = 0; j < 4; ++j) acc[j] = make_float4(0.f, 0.f, 0.f, 0.f);
#pragma unroll 4
    for (int kb = 0; kb < F_K / 4; ++kb) {
        float4 hv = hr[kb];
#pragma unroll
        for (int r = 0; r < 4; ++r) {
            float hk = r == 0 ? hv.x : r == 1 ? hv.y : r == 2 ? hv.z : hv.w;
            const float4* Wr = (const float4*)(W + (size_t)(kb * 4 + r) * 64 + (wave << 4));
#pragma unroll
            for (int j = 0; j < 4; ++j) {
                float4 w = Wr[j];          // uniform across wave -> s_load
                acc[j].x = fmaf(hk, w.x, acc[j].x);
                acc[j].y = fmaf(hk, w.y, acc[j].y);
                acc[j].z = fmaf(hk, w.z, acc[j].z);
                acc[j].w = fmaf(hk, w.w, acc[j].w);
            }
        }
    }
    float s = SCALED ? rsqrtf((float)cnt[v] + 1.0f) : 1.0f;
    __half* Pr = P + (size_t)v * 64 + (wave << 4);
    uint4 q0, q1;
    q0.x = pack_h2(acc[0].x * s, acc[0].y * s); q0.y = pack_h2(acc[0].z * s, acc[0].w * s);
    q0.z = pack_h2(acc[1].x * s, acc[1].y * s); q0.w = pack_h2(acc[1].z * s, acc[1].w * s);
    q1.x = pack_h2(acc[2].x * s, acc[2].y * s); q1.y = pack_h2(acc[2].z * s, acc[2].w * s);
    q1.z = pack_h2(acc[3].x * s, acc[3].y * s); q1.w = pack_h2(acc[3].z * s, acc[3].w * s);
    ((uint4*)Pr)[0] = q0;
    ((uint4*)Pr)[1] = q1;
}

// 72-window role split: 64 fill + 8 gemm per window -> co-resident overlap.
__global__ __launch_bounds__(256) void k_fused(
        const float* __restrict__ x, const float* __restrict__ W1,
        __half* __restrict__ P,
        const int* __restrict__ src, const int* __restrict__ dst,
        int* __restrict__ cnt, unsigned short* __restrict__ csr) {
    int w = blockIdx.x / 72;
    int r = blockIdx.x - w * 72;
    if (r >= 64) {
        gemm_body<F_IN, false>(x, W1, nullptr, cnt ? P : P, w * 8 + (r - 64));
    } else {
        int g     = r & 7;                 // == blockIdx&7 (XCD heuristic)
        int chunk = w * 8 + (r >> 3);      // [0,1024)
        int i     = chunk * blockDim.x + threadIdx.x;
        int4 d = ((const int4*)dst)[i];
#pragma unroll
        for (int k = 0; k < 4; ++k) {
            int dv = k == 0 ? d.x : k == 1 ? d.y : k == 2 ? d.z : d.w;
            if ((dv >> 13) == g) {
                int pos = atomicAdd(&cnt[dv], 1);
                csr[(dv << CAPSH) + pos] = (unsigned short)src[4 * i + k];
            }
        }
    }
}

// P1[v] *= rsqrt(cnt[v]+1). 4 threads per row, 32B (16 halves) each.
__global__ __launch_bounds__(256) void k_scale(
        __half* __restrict__ P, const int* __restrict__ cnt) {
    int t = blockIdx.x * blockDim.x + threadIdx.x;
    int v = t >> 2;
    float dv = rsqrtf((float)cnt[v] + 1.0f);
    uint4* p = (uint4*)(P + (size_t)v * 64) + (t & 3) * 2;
#pragma unroll
    for (int q = 0; q < 2; ++q) {
        uint4 u = p[q];
        unsigned int* w = (unsigned int*)&u;
#pragma unroll
        for (int j = 0; j < 4; ++j) {
            __half2 h = *(__half2*)&w[j];
            float2 f = __half22float2(h);
            w[j] = pack_h2(f.x * dv, f.y * dv);
        }
        p[q] = u;
    }
}

template <int F_K>
__global__ __launch_bounds__(256) void k_gemm(
        const float* __restrict__ h, const float* __restrict__ W,
        const int* __restrict__ cnt, __half* __restrict__ P) {
    gemm_body<F_K, true>(h, W, cnt, P, blockIdx.x);
}

// One wave per node; 16 branchless gathers in flight; next node's
// cnt/csr/self-row prefetched before current node's gather loop.
template <bool RELU>
__global__ __launch_bounds__(256) void k_agg(
        const __half* __restrict__ P, const unsigned short* __restrict__ csr,
        const int* __restrict__ cnt, const float* __restrict__ b,
        float* __restrict__ out) {
    int lane = threadIdx.x & 63;
    int sub  = lane >> 4;              // subgroup 0..3
    int col4 = lane & 15;              // 4-half column group
    int wave  = (blockIdx.x * blockDim.x + threadIdx.x) >> 6;
    int nwave = (gridDim.x * blockDim.x) >> 6;
    float4 bias = ((const float4*)b)[col4];
    int v = wave;
    int c = 0, sidx = 0;
    uint2 selfq = make_uint2(0u, 0u);
    if (v < N_NODES) {
        c     = cnt[v];
        sidx  = csr[(v << CAPSH) + lane];
        selfq = ((const uint2*)(P + (size_t)v * 64))[col4];
    }
    while (v < N_NODES) {
        // prefetch next node's control data + self row (hides csr latency)
        int vn = v + nwave;
        int cn = 0, sidxn = 0;
        uint2 selfqn = make_uint2(0u, 0u);
        if (vn < N_NODES) {
            cn     = cnt[vn];
            sidxn  = csr[(vn << CAPSH) + lane];
            selfqn = ((const uint2*)(P + (size_t)vn * 64))[col4];
        }
        float dv = rsqrtf((float)c + 1.0f);
        float4 acc = make_float4(0.f, 0.f, 0.f, 0.f);
        if (sub == 0) acc = h4_to_f4(selfq);     // self loop in subgroup 0
        for (int i = 0; i < c; i += 16) {
#pragma unroll
            for (int u = 0; u < 4; ++u) {
                int e = i + sub + 4 * u;         // <= 63 since c <= 64
                int s = __shfl(sidx, e);         // register-resident src id
                uint2 q = ((const uint2*)(P + (size_t)s * 64))[col4];
                bool m = e < c;                  // mask value, keep flow uniform
                q.x = m ? q.x : 0u;
                q.y = m ? q.y : 0u;
                float4 p = h4_to_f4(q);
                acc.x += p.x; acc.y += p.y; acc.z += p.z; acc.w += p.w;
            }
        }
        // fold the 4 subgroup partials: xor 16 then xor 32
        acc.x += __shfl_xor(acc.x, 16); acc.y += __shfl_xor(acc.y, 16);
        acc.z += __shfl_xor(acc.z, 16); acc.w += __shfl_xor(acc.w, 16);
        acc.x += __shfl_xor(acc.x, 32); acc.y += __shfl_xor(acc.y, 32);
        acc.z += __shfl_xor(acc.z, 32); acc.w += __shfl_xor(acc.w, 32);
        if (lane < 16) {
            float4 o;
            o.x = dv * acc.x + bias.x;
            o.y = dv * acc.y + bias.y;
            o.z = dv * acc.z + bias.z;
            o.w = dv * acc.w + bias.w;
            if (RELU) {
                o.x = o.x > 0.f ? o.x : 0.f;
                o.y = o.y > 0.f ? o.y : 0.f;
                o.z = o.z > 0.f ? o.z : 0.f;
                o.w = o.w > 0.f ? o.w : 0.f;
            }
            ((float4*)(out + (size_t)v * 64))[col4] = o;
        }
        v = vn; c = cn; sidx = sidxn; selfq = selfqn;
    }
}

extern "C" void kernel_launch(void* const* d_in, const int* in_sizes, int n_in,
                              void* d_out, int out_size, void* d_ws, size_t ws_size,
                              hipStream_t stream) {
    const float* x   = (const float*)d_in[0];
    const int*   ei  = (const int*)d_in[1];      // [2, E]: src row, dst row
    const float* W1  = (const float*)d_in[2];
    const float* b1  = (const float*)d_in[3];
    const float* W2  = (const float*)d_in[4];
    const float* b2  = (const float*)d_in[5];
    float*       out = (float*)d_out;

    const int* src = ei;
    const int* dst = ei + E_EDGES;

    int*            cnt = (int*)d_ws;                        // N ints
    unsigned short* csr = (unsigned short*)(cnt + N_NODES);  // N*64 u16 (8MB)
    __half*         P1  = (__half*)(csr + ((size_t)N_NODES << CAPSH)); // N*64 fp16
    __half*         P2  = P1 + (size_t)N_NODES * 64;         // N*64 fp16
    float*          H   = out;                               // layer-1 output in d_out

    hipMemsetAsync(cnt, 0, N_NODES * sizeof(int), stream);

    // gemm1 (unscaled) + CSR fill, interleaved 64:8 per 72-window
    k_fused<<<FUSED_BLOCKS, 256, 0, stream>>>(x, W1, P1, src, dst, cnt, csr);

    // P1 *= dinv  (prescale so aggregates need no per-edge cnt lookups)
    k_scale<<<N_NODES * 4 / 256, 256, 0, stream>>>(P1, cnt);

    // Layer 1 aggregate -> H (relu)
    k_agg<true><<<4096, 256, 0, stream>>>(P1, csr, cnt, b1, H);

    // Layer 2: H -> P2 (prescaled), aggregate -> out
    k_gemm<F_HID><<<N_NODES / 64, 256, 0, stream>>>(H, W2, cnt, P2);
    k_agg<false><<<4096, 256, 0, stream>>>(P2, csr, cnt, b2, out);
}